// Round 18
// baseline (170.947 us; speedup 1.0000x reference)
//
#include <hip/hip_runtime.h>
#include <hip/hip_bf16.h>
#include <math.h>

#define N_NODES 50000
#define N_EDGES 800000
#define DIMS 5
#define IN_C 32
#define OUT_C 32
#define FEAT 160            // DIMS*OUT_C
#define ATT_LD 65           // 2*OUT_C+1
#define NEG_SLOPE 0.2f
#define BSHIFT 7
#define BROWS 128                                   // rows per bucket
#define NBUCK ((N_NODES + BROWS - 1) / BROWS)       // 391
#define CAP 2560                                    // max edges/bucket (mean 2048, +11 sigma)
#define K1_EPB 1024
#define K1_BLOCKS ((N_EDGES + K1_EPB - 1) / K1_EPB) // 782

// ---- K1: per-block LDS histogram + per-edge local rank; fedge conversion ----
__global__ __launch_bounds__(1024) void hist_kernel(
        const int* __restrict__ ei, float* __restrict__ fedge,
        int* __restrict__ ghist, unsigned short* __restrict__ lofs) {
    __shared__ int hist[NBUCK];
    int blk = blockIdx.x, t = threadIdx.x;
    if (t < NBUCK) hist[t] = 0;
    __syncthreads();
    int e = blk * K1_EPB + t;
    if (e < N_EDGES) {
        int r = ei[e];
        int c = ei[N_EDGES + e];
        __builtin_nontemporal_store((float)r, &fedge[e]);
        __builtin_nontemporal_store((float)c, &fedge[N_EDGES + e]);
        int b = r >> BSHIFT;
        int lo = atomicAdd(&hist[b], 1);
        lofs[e] = (unsigned short)lo;
    }
    __syncthreads();
    if (t < NBUCK) ghist[blk * NBUCK + t] = hist[t];
}

// ---- K2a: column sums -> btot[b] ----
__global__ void colsum_kernel(const int* __restrict__ ghist, int* __restrict__ btot) {
    __shared__ int red[256];
    int b = blockIdx.x, t = threadIdx.x;
    int s = 0;
    for (int blk = t; blk < K1_BLOCKS; blk += 256) s += ghist[blk * NBUCK + b];
    red[t] = s;
    __syncthreads();
    for (int off = 128; off > 0; off >>= 1) {
        if (t < off) red[t] += red[t + off];
        __syncthreads();
    }
    if (t == 0) btot[b] = red[0];
}

// ---- K2b: exclusive scan of btot -> bbase ----
__global__ void bscan2_kernel(const int* __restrict__ btot, int* __restrict__ bbase) {
    __shared__ int buf[512];
    int t = threadIdx.x;
    int v = (t < NBUCK) ? btot[t] : 0;
    buf[t] = v;
    __syncthreads();
    for (int off = 1; off < 512; off <<= 1) {
        int add = (t >= off) ? buf[t - off] : 0;
        __syncthreads();
        buf[t] += add;
        __syncthreads();
    }
    if (t < NBUCK) bbase[t] = buf[t] - v;
}

// ---- K2c: per-bucket exclusive scan over 782 blocks -> base2[blk][b] (1024-wide) ----
__global__ __launch_bounds__(1024) void colscan_kernel(
        const int* __restrict__ ghist, const int* __restrict__ bbase,
        int* __restrict__ base2) {
    __shared__ int buf[1024];
    int b = blockIdx.x, t = threadIdx.x;
    int v = (t < K1_BLOCKS) ? ghist[t * NBUCK + b] : 0;
    buf[t] = v;
    __syncthreads();
    for (int off = 1; off < 1024; off <<= 1) {
        int add = (t >= off) ? buf[t - off] : 0;
        __syncthreads();
        buf[t] += add;
        __syncthreads();
    }
    if (t < K1_BLOCKS) base2[t * NBUCK + b] = bbase[b] + buf[t] - v;
}

// ---- K3: place edges into bucket-sorted staged[] with all 5 es embedded ----
// staged int4: x = c | rl<<16 ; y = es0|es1<<16 ; z = es2|es3<<16 ; w = es4
__global__ __launch_bounds__(1024) void place_kernel(
        const int* __restrict__ ei, const unsigned short* __restrict__ lofs,
        const int* __restrict__ base2,
        const float* __restrict__ edge_attr,
        const float* __restrict__ ai, const float* __restrict__ aj,
        const float* __restrict__ att,
        int4* __restrict__ staged) {
    __shared__ int lbase[NBUCK];
    __shared__ float satte[DIMS];
    int blk = blockIdx.x, t = threadIdx.x;
    if (t < NBUCK) lbase[t] = base2[blk * NBUCK + t];
    if (t < DIMS) satte[t] = att[t * ATT_LD + 2 * OUT_C];
    __syncthreads();
    int e = blk * K1_EPB + t;
    if (e < N_EDGES) {
        int r = ei[e];
        int c = ei[N_EDGES + e];
        const float* air = ai + r * DIMS;
        const float* ajr = aj + c * DIMS;
        const float* ea  = edge_attr + (size_t)e * DIMS;
        unsigned es[DIMS];
#pragma unroll
        for (int d = 0; d < DIMS; ++d) {
            float s = air[d] + ajr[d] + ea[d] * satte[d];
            s = (s > 0.f) ? s : NEG_SLOPE * s;
            __hip_bfloat16 h = __float2bfloat16(__expf(s));
            es[d] = (unsigned)*(unsigned short*)&h;
        }
        int4 st;
        st.x = c | ((r & (BROWS - 1)) << 16);
        st.y = (int)(es[0] | (es[1] << 16));
        st.z = (int)(es[2] | (es[3] << 16));
        st.w = (int)es[4];
        staged[lbase[r >> BSHIFT] + (int)lofs[e]] = st;
    }
}

// ---- build: per-bucket CSR in LDS -> rowStart + 5-stream packed csrd ----
__global__ __launch_bounds__(256) void build_kernel(
        const int4* __restrict__ staged, const int* __restrict__ btot,
        const int* __restrict__ bbase,
        unsigned* __restrict__ csrd, int* __restrict__ rowStart) {
    __shared__ int4 sst[CAP];
    __shared__ int rcount[BROWS];
    __shared__ int rexcl[BROWS];
    __shared__ int sbuf[BROWS];
    int b = blockIdx.x;
    int t = threadIdx.x;
    int cnt  = btot[b];
    int base = bbase[b];
    const int4* sg = staged + base;
    for (int i = t; i < cnt; i += 256) sst[i] = sg[i];
    if (t < BROWS) rcount[t] = 0;
    __syncthreads();
    for (int i = t; i < cnt; i += 256)
        atomicAdd(&rcount[((unsigned)sst[i].x >> 16) & (BROWS - 1)], 1);
    __syncthreads();
    if (t < BROWS) sbuf[t] = rcount[t];
    __syncthreads();
    for (int off = 1; off < BROWS; off <<= 1) {
        int add = (t < BROWS && t >= off) ? sbuf[t - off] : 0;
        __syncthreads();
        if (t < BROWS) sbuf[t] += add;
        __syncthreads();
    }
    if (t < BROWS) {
        rexcl[t] = sbuf[t] - rcount[t];
        int idx = b * BROWS + t;
        if (idx <= N_NODES) rowStart[idx] = base + rexcl[t];
        rcount[t] = 0;                 // reuse as per-row cursor
    }
    __syncthreads();
    for (int i = t; i < cnt; i += 256) {
        int4 p = sst[i];
        int rl = ((unsigned)p.x >> 16) & (BROWS - 1);
        unsigned c = (unsigned)p.x & 0xffffu;
        int lp = atomicAdd(&rcount[rl], 1);
        int pos = base + rexcl[rl] + lp;
        unsigned es0 = (unsigned)p.y & 0xffffu;
        unsigned es1 = (unsigned)p.y >> 16;
        unsigned es2v = (unsigned)p.z & 0xffffu;
        unsigned es3 = (unsigned)p.z >> 16;
        unsigned es4 = (unsigned)p.w & 0xffffu;
        csrd[0 * N_EDGES + pos] = c | (es0 << 16);
        csrd[1 * N_EDGES + pos] = c | (es1 << 16);
        csrd[2 * N_EDGES + pos] = c | (es2v << 16);
        csrd[3 * N_EDGES + pos] = c | (es3 << 16);
        csrd[4 * N_EDGES + pos] = c | (es4 << 16);
    }
}

// ---- fused h (bf16) + ai/aj. thread = (node-pair, og): each W float4 feeds 8 FMAs ----
__global__ __launch_bounds__(256) void hfused_kernel(
        const float* __restrict__ x, const float* __restrict__ W,
        const float* __restrict__ att,
        __hip_bfloat16* __restrict__ h2,
        float* __restrict__ ai, float* __restrict__ aj) {
    int idx = blockIdx.x * 256 + threadIdx.x;
    int pr = idx >> 3;                 // node pair
    int og = idx & 7;
    int n0 = pr * 2;
    if (n0 >= N_NODES) return;         // N even -> n0+1 valid
    const float4* xr0 = (const float4*)(x + (size_t)n0 * FEAT);
    const float4* xr1 = xr0 + 40;

    float acc0[DIMS][4], acc1[DIMS][4];
#pragma unroll
    for (int d = 0; d < DIMS; ++d)
#pragma unroll
        for (int q = 0; q < 4; ++q) { acc0[d][q] = 0.f; acc1[d][q] = 0.f; }

#pragma unroll
    for (int ib = 0; ib < 8; ++ib) {
        float xs0[20], xs1[20];
#pragma unroll
        for (int q = 0; q < 5; ++q) {
            float4 v0 = xr0[ib * 5 + q];
            float4 v1 = xr1[ib * 5 + q];
            xs0[q * 4 + 0] = v0.x; xs0[q * 4 + 1] = v0.y;
            xs0[q * 4 + 2] = v0.z; xs0[q * 4 + 3] = v0.w;
            xs1[q * 4 + 0] = v1.x; xs1[q * 4 + 1] = v1.y;
            xs1[q * 4 + 2] = v1.z; xs1[q * 4 + 3] = v1.w;
        }
#pragma unroll
        for (int ii = 0; ii < 4; ++ii) {
            int i = ib * 4 + ii;
#pragma unroll
            for (int d = 0; d < DIMS; ++d) {
                float4 wv = *(const float4*)(W + ((d * IN_C + i) * OUT_C) + og * 4);
                float xv0 = xs0[ii * 5 + d];
                float xv1 = xs1[ii * 5 + d];
                acc0[d][0] += xv0 * wv.x; acc0[d][1] += xv0 * wv.y;
                acc0[d][2] += xv0 * wv.z; acc0[d][3] += xv0 * wv.w;
                acc1[d][0] += xv1 * wv.x; acc1[d][1] += xv1 * wv.y;
                acc1[d][2] += xv1 * wv.z; acc1[d][3] += xv1 * wv.w;
            }
        }
    }

    __hip_bfloat16* hp0 = h2 + (size_t)n0 * FEAT + og * 4;
#pragma unroll
    for (int d = 0; d < DIMS; ++d) {
        union { __hip_bfloat16 h[4]; uint2 u; } pk;
        pk.h[0] = __float2bfloat16(acc0[d][0]);
        pk.h[1] = __float2bfloat16(acc0[d][1]);
        pk.h[2] = __float2bfloat16(acc0[d][2]);
        pk.h[3] = __float2bfloat16(acc0[d][3]);
        *(uint2*)(hp0 + d * OUT_C) = pk.u;
    }
    __hip_bfloat16* hp1 = hp0 + FEAT;
#pragma unroll
    for (int d = 0; d < DIMS; ++d) {
        union { __hip_bfloat16 h[4]; uint2 u; } pk;
        pk.h[0] = __float2bfloat16(acc1[d][0]);
        pk.h[1] = __float2bfloat16(acc1[d][1]);
        pk.h[2] = __float2bfloat16(acc1[d][2]);
        pk.h[3] = __float2bfloat16(acc1[d][3]);
        *(uint2*)(hp1 + d * OUT_C) = pk.u;
    }

    float pa0[DIMS], pb0[DIMS], pa1[DIMS], pb1[DIMS];
#pragma unroll
    for (int d = 0; d < DIMS; ++d) {
        const float* at = att + d * ATT_LD + og * 4;
        const float* bt = at + OUT_C;
        pa0[d] = acc0[d][0] * at[0] + acc0[d][1] * at[1] + acc0[d][2] * at[2] + acc0[d][3] * at[3];
        pb0[d] = acc0[d][0] * bt[0] + acc0[d][1] * bt[1] + acc0[d][2] * bt[2] + acc0[d][3] * bt[3];
        pa1[d] = acc1[d][0] * at[0] + acc1[d][1] * at[1] + acc1[d][2] * at[2] + acc1[d][3] * at[3];
        pb1[d] = acc1[d][0] * bt[0] + acc1[d][1] * bt[1] + acc1[d][2] * bt[2] + acc1[d][3] * bt[3];
    }
#pragma unroll
    for (int m = 1; m < 8; m <<= 1) {
#pragma unroll
        for (int d = 0; d < DIMS; ++d) {
            pa0[d] += __shfl_xor(pa0[d], m, 8);
            pb0[d] += __shfl_xor(pb0[d], m, 8);
            pa1[d] += __shfl_xor(pa1[d], m, 8);
            pb1[d] += __shfl_xor(pb1[d], m, 8);
        }
    }
    if (og == 0) {
#pragma unroll
        for (int d = 0; d < DIMS; ++d) {
            ai[n0 * DIMS + d] = pa0[d];
            aj[n0 * DIMS + d] = pb0[d];
            ai[(n0 + 1) * DIMS + d] = pa1[d];
            aj[(n0 + 1) * DIMS + d] = pb1[d];
        }
    }
}

__device__ inline float bf2f(unsigned short u) {
    return __uint_as_float(((unsigned)u) << 16);
}

// ---- out: 320-thr blocks, 8 nodes/block, 40 lanes/node; packed per-d csr stream,
//      masked final batch + prefetch ----
__global__ __launch_bounds__(320) void out_kernel(
        const __hip_bfloat16* __restrict__ h2,
        const unsigned* __restrict__ csrd,
        const int* __restrict__ rowStart,
        float* __restrict__ out, float* __restrict__ ssum) {
    int g = threadIdx.x / 40;          // node group 0..7
    int l = threadIdx.x - g * 40;      // 0..39
    int node = blockIdx.x * 8 + g;
    int d = l >> 3;                    // 8 lanes per d
    const unsigned* cs = csrd + (size_t)d * N_EDGES;
    int start = rowStart[node];
    int end   = rowStart[node + 1];
    float a0 = 0.f, a1 = 0.f, a2 = 0.f, a3 = 0.f, ss = 0.f;
    if (end > start) {
        int last = end - 1;
        int k = start;
        unsigned ceA[8];
#pragma unroll
        for (int u = 0; u < 8; ++u) {
            int kk = k + u;
            ceA[u] = cs[kk <= last ? kk : last];
        }
        while (true) {
            int kn = k + 8;
            bool more = (kn < end);
            float av[8]; uint2 hv[8]; unsigned ceB[8];
#pragma unroll
            for (int u = 0; u < 8; ++u) {
                float a = bf2f((unsigned short)(ceA[u] >> 16));
                av[u] = (k + u < end) ? a : 0.f;
            }
#pragma unroll
            for (int u = 0; u < 8; ++u)
                hv[u] = *(const uint2*)(h2 + (size_t)(ceA[u] & 0xffffu) * FEAT + l * 4);
            if (more) {
#pragma unroll
                for (int u = 0; u < 8; ++u) {
                    int kk = kn + u;
                    ceB[u] = cs[kk <= last ? kk : last];
                }
            }
#pragma unroll
            for (int u = 0; u < 8; ++u) {
                float a = av[u];
                ss += a;
                a0 += a * __uint_as_float(hv[u].x << 16);
                a1 += a * __uint_as_float(hv[u].x & 0xffff0000u);
                a2 += a * __uint_as_float(hv[u].y << 16);
                a3 += a * __uint_as_float(hv[u].y & 0xffff0000u);
            }
            if (!more) break;
            k = kn;
#pragma unroll
            for (int u = 0; u < 8; ++u) ceA[u] = ceB[u];
        }
    }
    float inv = 1.f / (ss + 1e-16f);
    union { float f[4]; unsigned long long u[2]; } o;
    o.f[0] = a0 * inv; o.f[1] = a1 * inv; o.f[2] = a2 * inv; o.f[3] = a3 * inv;
    unsigned long long* op = (unsigned long long*)(out + (size_t)node * FEAT + l * 4);
    __builtin_nontemporal_store(o.u[0], op);
    __builtin_nontemporal_store(o.u[1], op + 1);
    if ((l & 7) == 0) ssum[node * DIMS + d] = ss;
}

// ---- alpha: recompute es coalesced (edge order), divide by ssum[row] ----
__global__ void alpha_kernel(const int* __restrict__ ei,
                             const float* __restrict__ edge_attr,
                             const float* __restrict__ ai, const float* __restrict__ aj,
                             const float* __restrict__ att,
                             const float* __restrict__ ssum,
                             float* __restrict__ alpha_buf) {
    int idx = blockIdx.x * blockDim.x + threadIdx.x;
    if (idx >= N_EDGES * DIMS) return;
    int e = idx / DIMS;
    int d = idx - e * DIMS;
    int r = ei[e];
    int c = ei[N_EDGES + e];
    float s = ai[r * DIMS + d] + aj[c * DIMS + d]
            + edge_attr[idx] * att[d * ATT_LD + 2 * OUT_C];
    s = (s > 0.f) ? s : NEG_SLOPE * s;
    __hip_bfloat16 h = __float2bfloat16(__expf(s));
    float a = bf2f(*(unsigned short*)&h) / (ssum[r * DIMS + d] + 1e-16f);
    __builtin_nontemporal_store(a, &alpha_buf[idx]);
}

extern "C" void kernel_launch(void* const* d_in, const int* in_sizes, int n_in,
                              void* d_out, int out_size, void* d_ws, size_t ws_size,
                              hipStream_t stream) {
    const float* x         = (const float*)d_in[0];
    const int*   ei        = (const int*)d_in[1];
    const float* edge_attr = (const float*)d_in[2];
    const float* W         = (const float*)d_in[3];
    const float* att       = (const float*)d_in[4];

    float* out_buf   = (float*)d_out;                       // 8,000,000 f32
    float* alpha_buf = out_buf + (size_t)N_NODES * FEAT;    // 4,000,000 f32 (scratch until alpha)
    float* fedge     = alpha_buf + (size_t)N_EDGES * DIMS;  // 1,600,000 f32

    // scratch inside the alpha output region (dead until alpha_kernel runs last):
    int4* staged = (int4*)alpha_buf;                        // 12,800,000 B
    unsigned short* lofs = (unsigned short*)((char*)alpha_buf + 12800000); // 1,600,000 B

    char* wsb = (char*)d_ws;
    __hip_bfloat16* h2 = (__hip_bfloat16*)wsb;              //  0 .. 16,000,000
    float* ai     = (float*)(wsb + 16000000);               // 1,000,000 B
    float* aj     = (float*)(wsb + 17000000);               // 1,000,000 B
    float* ssum   = (float*)(wsb + 18000000);               // 1,000,000 B
    unsigned* csrd = (unsigned*)(wsb + 19000000);           // 16,000,000 B (5 streams x 3.2MB)
    int* ghist    = (int*)(wsb + 35000000);                 // 782*391*4 = 1,223,048 B
    int* base2    = (int*)(wsb + 36224000);                 // 1,223,048 B
    int* btot     = (int*)(wsb + 37448000);                 // 1,564 B
    int* bbase    = (int*)(wsb + 37450000);                 // 1,564 B
    int* rowStart = (int*)(wsb + 37452000);                 // 200,004 B -> end ~37.65 MB

    const int B = 256;

    hist_kernel<<<K1_BLOCKS, 1024, 0, stream>>>(ei, fedge, ghist, lofs);
    hfused_kernel<<<(N_NODES / 2 * 8 + B - 1) / B, B, 0, stream>>>(x, W, att, h2, ai, aj);
    colsum_kernel<<<NBUCK, 256, 0, stream>>>(ghist, btot);
    bscan2_kernel<<<1, 512, 0, stream>>>(btot, bbase);
    colscan_kernel<<<NBUCK, 1024, 0, stream>>>(ghist, bbase, base2);
    place_kernel<<<K1_BLOCKS, 1024, 0, stream>>>(ei, lofs, base2, edge_attr,
                                                 ai, aj, att, staged);
    build_kernel<<<NBUCK, 256, 0, stream>>>(staged, btot, bbase, csrd, rowStart);
    out_kernel<<<N_NODES / 8, 320, 0, stream>>>(h2, csrd, rowStart, out_buf, ssum);
    alpha_kernel<<<(N_EDGES * DIMS + B - 1) / B, B, 0, stream>>>(ei, edge_attr, ai, aj, att,
                                                                 ssum, alpha_buf);
}

// Round 19
// 152.060 us; speedup vs baseline: 1.1242x; 1.1242x over previous
//
#include <hip/hip_runtime.h>
#include <hip/hip_bf16.h>
#include <math.h>

#define N_NODES 50000
#define N_EDGES 800000
#define DIMS 5
#define IN_C 32
#define OUT_C 32
#define FEAT 160            // DIMS*OUT_C
#define ATT_LD 65           // 2*OUT_C+1
#define NEG_SLOPE 0.2f
#define BSHIFT 7
#define BROWS 128                                   // rows per bucket
#define NBUCK ((N_NODES + BROWS - 1) / BROWS)       // 391
#define CAP 2560                                    // max edges/bucket (mean 2048, +11 sigma)
#define K1_EPB 4096
#define K1_BLOCKS ((N_EDGES + K1_EPB - 1) / K1_EPB) // 196

// ---- K1: per-block LDS histogram + per-edge local rank; fedge conversion ----
__global__ __launch_bounds__(1024) void hist_kernel(
        const int* __restrict__ ei, float* __restrict__ fedge,
        int* __restrict__ ghist, unsigned short* __restrict__ lofs) {
    __shared__ int hist[NBUCK];
    int blk = blockIdx.x, t = threadIdx.x;
    if (t < NBUCK) hist[t] = 0;
    __syncthreads();
#pragma unroll
    for (int u = 0; u < 4; ++u) {
        int e = blk * K1_EPB + u * 1024 + t;
        if (e < N_EDGES) {
            int r = ei[e];
            int c = ei[N_EDGES + e];
            __builtin_nontemporal_store((float)r, &fedge[e]);
            __builtin_nontemporal_store((float)c, &fedge[N_EDGES + e]);
            int b = r >> BSHIFT;
            int lo = atomicAdd(&hist[b], 1);
            lofs[e] = (unsigned short)lo;
        }
    }
    __syncthreads();
    if (t < NBUCK) ghist[blk * NBUCK + t] = hist[t];
}

// ---- K2a: column sums -> btot[b] ----
__global__ void colsum_kernel(const int* __restrict__ ghist, int* __restrict__ btot) {
    __shared__ int red[256];
    int b = blockIdx.x, t = threadIdx.x;
    int s = 0;
    for (int blk = t; blk < K1_BLOCKS; blk += 256) s += ghist[blk * NBUCK + b];
    red[t] = s;
    __syncthreads();
    for (int off = 128; off > 0; off >>= 1) {
        if (t < off) red[t] += red[t + off];
        __syncthreads();
    }
    if (t == 0) btot[b] = red[0];
}

// ---- K2b: exclusive scan of btot -> bbase ----
__global__ void bscan2_kernel(const int* __restrict__ btot, int* __restrict__ bbase) {
    __shared__ int buf[512];
    int t = threadIdx.x;
    int v = (t < NBUCK) ? btot[t] : 0;
    buf[t] = v;
    __syncthreads();
    for (int off = 1; off < 512; off <<= 1) {
        int add = (t >= off) ? buf[t - off] : 0;
        __syncthreads();
        buf[t] += add;
        __syncthreads();
    }
    if (t < NBUCK) bbase[t] = buf[t] - v;
}

// ---- K2c: per-bucket exclusive scan over blocks -> base2[blk][b] ----
__global__ void colscan_kernel(const int* __restrict__ ghist, const int* __restrict__ bbase,
                               int* __restrict__ base2) {
    __shared__ int buf[256];
    int b = blockIdx.x, t = threadIdx.x;
    int v = (t < K1_BLOCKS) ? ghist[t * NBUCK + b] : 0;
    buf[t] = v;
    __syncthreads();
    for (int off = 1; off < 256; off <<= 1) {
        int add = (t >= off) ? buf[t - off] : 0;
        __syncthreads();
        buf[t] += add;
        __syncthreads();
    }
    if (t < K1_BLOCKS) base2[t * NBUCK + b] = bbase[b] + buf[t] - v;
}

// ---- K3: place edges into bucket-sorted staged[] with all 5 es embedded ----
// staged int4: x = c | rl<<16 ; y = es0|es1<<16 ; z = es2|es3<<16 ; w = es4
__global__ __launch_bounds__(1024) void place_kernel(
        const int* __restrict__ ei, const unsigned short* __restrict__ lofs,
        const int* __restrict__ base2,
        const float* __restrict__ edge_attr,
        const float* __restrict__ ai, const float* __restrict__ aj,
        const float* __restrict__ att,
        int4* __restrict__ staged) {
    __shared__ int lbase[NBUCK];
    __shared__ float satte[DIMS];
    int blk = blockIdx.x, t = threadIdx.x;
    if (t < NBUCK) lbase[t] = base2[blk * NBUCK + t];
    if (t < DIMS) satte[t] = att[t * ATT_LD + 2 * OUT_C];
    __syncthreads();
#pragma unroll
    for (int u = 0; u < 4; ++u) {
        int e = blk * K1_EPB + u * 1024 + t;
        if (e < N_EDGES) {
            int r = ei[e];
            int c = ei[N_EDGES + e];
            const float* air = ai + r * DIMS;
            const float* ajr = aj + c * DIMS;
            const float* ea  = edge_attr + (size_t)e * DIMS;
            unsigned es[DIMS];
#pragma unroll
            for (int d = 0; d < DIMS; ++d) {
                float s = air[d] + ajr[d] + ea[d] * satte[d];
                s = (s > 0.f) ? s : NEG_SLOPE * s;
                __hip_bfloat16 h = __float2bfloat16(__expf(s));
                es[d] = (unsigned)*(unsigned short*)&h;
            }
            int4 st;
            st.x = c | ((r & (BROWS - 1)) << 16);
            st.y = (int)(es[0] | (es[1] << 16));
            st.z = (int)(es[2] | (es[3] << 16));
            st.w = (int)es[4];
            staged[lbase[r >> BSHIFT] + (int)lofs[e]] = st;
        }
    }
}

// ---- build: per-bucket CSR in LDS -> rowStart + 5-stream packed csrd ----
__global__ __launch_bounds__(256) void build_kernel(
        const int4* __restrict__ staged, const int* __restrict__ btot,
        const int* __restrict__ bbase,
        unsigned* __restrict__ csrd, int* __restrict__ rowStart) {
    __shared__ int4 sst[CAP];
    __shared__ int rcount[BROWS];
    __shared__ int rexcl[BROWS];
    __shared__ int sbuf[BROWS];
    int b = blockIdx.x;
    int t = threadIdx.x;
    int cnt  = btot[b];
    int base = bbase[b];
    const int4* sg = staged + base;
    for (int i = t; i < cnt; i += 256) sst[i] = sg[i];
    if (t < BROWS) rcount[t] = 0;
    __syncthreads();
    for (int i = t; i < cnt; i += 256)
        atomicAdd(&rcount[((unsigned)sst[i].x >> 16) & (BROWS - 1)], 1);
    __syncthreads();
    if (t < BROWS) sbuf[t] = rcount[t];
    __syncthreads();
    for (int off = 1; off < BROWS; off <<= 1) {
        int add = (t < BROWS && t >= off) ? sbuf[t - off] : 0;
        __syncthreads();
        if (t < BROWS) sbuf[t] += add;
        __syncthreads();
    }
    if (t < BROWS) {
        rexcl[t] = sbuf[t] - rcount[t];
        int idx = b * BROWS + t;
        if (idx <= N_NODES) rowStart[idx] = base + rexcl[t];
        rcount[t] = 0;                 // reuse as per-row cursor
    }
    __syncthreads();
    for (int i = t; i < cnt; i += 256) {
        int4 p = sst[i];
        int rl = ((unsigned)p.x >> 16) & (BROWS - 1);
        unsigned c = (unsigned)p.x & 0xffffu;
        int lp = atomicAdd(&rcount[rl], 1);
        int pos = base + rexcl[rl] + lp;
        unsigned es0 = (unsigned)p.y & 0xffffu;
        unsigned es1 = (unsigned)p.y >> 16;
        unsigned es2v = (unsigned)p.z & 0xffffu;
        unsigned es3 = (unsigned)p.z >> 16;
        unsigned es4 = (unsigned)p.w & 0xffffu;
        csrd[0 * N_EDGES + pos] = c | (es0 << 16);
        csrd[1 * N_EDGES + pos] = c | (es1 << 16);
        csrd[2 * N_EDGES + pos] = c | (es2v << 16);
        csrd[3 * N_EDGES + pos] = c | (es3 << 16);
        csrd[4 * N_EDGES + pos] = c | (es4 << 16);
    }
}

// ---- fused h (bf16) + ai/aj. thread = (node-pair, og); W staged in LDS (20 KB) ----
__global__ __launch_bounds__(256) void hfused_kernel(
        const float* __restrict__ x, const float* __restrict__ W,
        const float* __restrict__ att,
        __hip_bfloat16* __restrict__ h2,
        float* __restrict__ ai, float* __restrict__ aj) {
    __shared__ float sW[DIMS * IN_C * OUT_C];   // 5120 f32 = 20,480 B
    int tid = threadIdx.x;
    // cooperative W stage: 1280 float4 / 256 threads = 5 each (all threads participate)
    {
        const float4* Wg = (const float4*)W;
        float4* sW4 = (float4*)sW;
#pragma unroll
        for (int j = 0; j < 5; ++j)
            sW4[j * 256 + tid] = Wg[j * 256 + tid];
    }
    __syncthreads();

    int idx = blockIdx.x * 256 + tid;
    int pr = idx >> 3;                 // node pair
    int og = idx & 7;
    int n0 = pr * 2;
    if (n0 >= N_NODES) return;         // safe: after staging+barrier
    const float4* xr0 = (const float4*)(x + (size_t)n0 * FEAT);
    const float4* xr1 = xr0 + 40;

    float acc0[DIMS][4], acc1[DIMS][4];
#pragma unroll
    for (int d = 0; d < DIMS; ++d)
#pragma unroll
        for (int q = 0; q < 4; ++q) { acc0[d][q] = 0.f; acc1[d][q] = 0.f; }

#pragma unroll
    for (int ib = 0; ib < 8; ++ib) {
        float xs0[20], xs1[20];
#pragma unroll
        for (int q = 0; q < 5; ++q) {
            float4 v0 = xr0[ib * 5 + q];
            float4 v1 = xr1[ib * 5 + q];
            xs0[q * 4 + 0] = v0.x; xs0[q * 4 + 1] = v0.y;
            xs0[q * 4 + 2] = v0.z; xs0[q * 4 + 3] = v0.w;
            xs1[q * 4 + 0] = v1.x; xs1[q * 4 + 1] = v1.y;
            xs1[q * 4 + 2] = v1.z; xs1[q * 4 + 3] = v1.w;
        }
#pragma unroll
        for (int ii = 0; ii < 4; ++ii) {
            int i = ib * 4 + ii;
#pragma unroll
            for (int d = 0; d < DIMS; ++d) {
                float4 wv = *(const float4*)(sW + ((d * IN_C + i) * OUT_C) + og * 4);
                float xv0 = xs0[ii * 5 + d];
                float xv1 = xs1[ii * 5 + d];
                acc0[d][0] += xv0 * wv.x; acc0[d][1] += xv0 * wv.y;
                acc0[d][2] += xv0 * wv.z; acc0[d][3] += xv0 * wv.w;
                acc1[d][0] += xv1 * wv.x; acc1[d][1] += xv1 * wv.y;
                acc1[d][2] += xv1 * wv.z; acc1[d][3] += xv1 * wv.w;
            }
        }
    }

    __hip_bfloat16* hp0 = h2 + (size_t)n0 * FEAT + og * 4;
#pragma unroll
    for (int d = 0; d < DIMS; ++d) {
        union { __hip_bfloat16 h[4]; uint2 u; } pk;
        pk.h[0] = __float2bfloat16(acc0[d][0]);
        pk.h[1] = __float2bfloat16(acc0[d][1]);
        pk.h[2] = __float2bfloat16(acc0[d][2]);
        pk.h[3] = __float2bfloat16(acc0[d][3]);
        *(uint2*)(hp0 + d * OUT_C) = pk.u;
    }
    __hip_bfloat16* hp1 = hp0 + FEAT;
#pragma unroll
    for (int d = 0; d < DIMS; ++d) {
        union { __hip_bfloat16 h[4]; uint2 u; } pk;
        pk.h[0] = __float2bfloat16(acc1[d][0]);
        pk.h[1] = __float2bfloat16(acc1[d][1]);
        pk.h[2] = __float2bfloat16(acc1[d][2]);
        pk.h[3] = __float2bfloat16(acc1[d][3]);
        *(uint2*)(hp1 + d * OUT_C) = pk.u;
    }

    float pa0[DIMS], pb0[DIMS], pa1[DIMS], pb1[DIMS];
#pragma unroll
    for (int d = 0; d < DIMS; ++d) {
        const float* at = att + d * ATT_LD + og * 4;
        const float* bt = at + OUT_C;
        pa0[d] = acc0[d][0] * at[0] + acc0[d][1] * at[1] + acc0[d][2] * at[2] + acc0[d][3] * at[3];
        pb0[d] = acc0[d][0] * bt[0] + acc0[d][1] * bt[1] + acc0[d][2] * bt[2] + acc0[d][3] * bt[3];
        pa1[d] = acc1[d][0] * at[0] + acc1[d][1] * at[1] + acc1[d][2] * at[2] + acc1[d][3] * at[3];
        pb1[d] = acc1[d][0] * bt[0] + acc1[d][1] * bt[1] + acc1[d][2] * bt[2] + acc1[d][3] * bt[3];
    }
#pragma unroll
    for (int m = 1; m < 8; m <<= 1) {
#pragma unroll
        for (int d = 0; d < DIMS; ++d) {
            pa0[d] += __shfl_xor(pa0[d], m, 8);
            pb0[d] += __shfl_xor(pb0[d], m, 8);
            pa1[d] += __shfl_xor(pa1[d], m, 8);
            pb1[d] += __shfl_xor(pb1[d], m, 8);
        }
    }
    if (og == 0) {
#pragma unroll
        for (int d = 0; d < DIMS; ++d) {
            ai[n0 * DIMS + d] = pa0[d];
            aj[n0 * DIMS + d] = pb0[d];
            ai[(n0 + 1) * DIMS + d] = pa1[d];
            aj[(n0 + 1) * DIMS + d] = pb1[d];
        }
    }
}

__device__ inline float bf2f(unsigned short u) {
    return __uint_as_float(((unsigned)u) << 16);
}

// ---- out: 320-thr blocks, 8 nodes/block, 40 lanes/node; packed per-d csr stream,
//      masked final batch + prefetch ----
__global__ __launch_bounds__(320) void out_kernel(
        const __hip_bfloat16* __restrict__ h2,
        const unsigned* __restrict__ csrd,
        const int* __restrict__ rowStart,
        float* __restrict__ out, float* __restrict__ ssum) {
    int g = threadIdx.x / 40;          // node group 0..7
    int l = threadIdx.x - g * 40;      // 0..39
    int node = blockIdx.x * 8 + g;
    int d = l >> 3;                    // 8 lanes per d
    const unsigned* cs = csrd + (size_t)d * N_EDGES;
    int start = rowStart[node];
    int end   = rowStart[node + 1];
    float a0 = 0.f, a1 = 0.f, a2 = 0.f, a3 = 0.f, ss = 0.f;
    if (end > start) {
        int last = end - 1;
        int k = start;
        unsigned ceA[8];
#pragma unroll
        for (int u = 0; u < 8; ++u) {
            int kk = k + u;
            ceA[u] = cs[kk <= last ? kk : last];
        }
        while (true) {
            int kn = k + 8;
            bool more = (kn < end);
            float av[8]; uint2 hv[8]; unsigned ceB[8];
#pragma unroll
            for (int u = 0; u < 8; ++u) {
                float a = bf2f((unsigned short)(ceA[u] >> 16));
                av[u] = (k + u < end) ? a : 0.f;
            }
#pragma unroll
            for (int u = 0; u < 8; ++u)
                hv[u] = *(const uint2*)(h2 + (size_t)(ceA[u] & 0xffffu) * FEAT + l * 4);
            if (more) {
#pragma unroll
                for (int u = 0; u < 8; ++u) {
                    int kk = kn + u;
                    ceB[u] = cs[kk <= last ? kk : last];
                }
            }
#pragma unroll
            for (int u = 0; u < 8; ++u) {
                float a = av[u];
                ss += a;
                a0 += a * __uint_as_float(hv[u].x << 16);
                a1 += a * __uint_as_float(hv[u].x & 0xffff0000u);
                a2 += a * __uint_as_float(hv[u].y << 16);
                a3 += a * __uint_as_float(hv[u].y & 0xffff0000u);
            }
            if (!more) break;
            k = kn;
#pragma unroll
            for (int u = 0; u < 8; ++u) ceA[u] = ceB[u];
        }
    }
    float inv = 1.f / (ss + 1e-16f);
    union { float f[4]; unsigned long long u[2]; } o;
    o.f[0] = a0 * inv; o.f[1] = a1 * inv; o.f[2] = a2 * inv; o.f[3] = a3 * inv;
    unsigned long long* op = (unsigned long long*)(out + (size_t)node * FEAT + l * 4);
    __builtin_nontemporal_store(o.u[0], op);
    __builtin_nontemporal_store(o.u[1], op + 1);
    if ((l & 7) == 0) ssum[node * DIMS + d] = ss;
}

// ---- alpha: recompute es coalesced (edge order), divide by ssum[row] ----
__global__ void alpha_kernel(const int* __restrict__ ei,
                             const float* __restrict__ edge_attr,
                             const float* __restrict__ ai, const float* __restrict__ aj,
                             const float* __restrict__ att,
                             const float* __restrict__ ssum,
                             float* __restrict__ alpha_buf) {
    int idx = blockIdx.x * blockDim.x + threadIdx.x;
    if (idx >= N_EDGES * DIMS) return;
    int e = idx / DIMS;
    int d = idx - e * DIMS;
    int r = ei[e];
    int c = ei[N_EDGES + e];
    float s = ai[r * DIMS + d] + aj[c * DIMS + d]
            + edge_attr[idx] * att[d * ATT_LD + 2 * OUT_C];
    s = (s > 0.f) ? s : NEG_SLOPE * s;
    __hip_bfloat16 h = __float2bfloat16(__expf(s));
    float a = bf2f(*(unsigned short*)&h) / (ssum[r * DIMS + d] + 1e-16f);
    __builtin_nontemporal_store(a, &alpha_buf[idx]);
}

extern "C" void kernel_launch(void* const* d_in, const int* in_sizes, int n_in,
                              void* d_out, int out_size, void* d_ws, size_t ws_size,
                              hipStream_t stream) {
    const float* x         = (const float*)d_in[0];
    const int*   ei        = (const int*)d_in[1];
    const float* edge_attr = (const float*)d_in[2];
    const float* W         = (const float*)d_in[3];
    const float* att       = (const float*)d_in[4];

    float* out_buf   = (float*)d_out;                       // 8,000,000 f32
    float* alpha_buf = out_buf + (size_t)N_NODES * FEAT;    // 4,000,000 f32 (scratch until alpha)
    float* fedge     = alpha_buf + (size_t)N_EDGES * DIMS;  // 1,600,000 f32

    // scratch inside the alpha output region (dead until alpha_kernel runs last):
    int4* staged = (int4*)alpha_buf;                        // 12,800,000 B
    unsigned short* lofs = (unsigned short*)((char*)alpha_buf + 12800000); // 1,600,000 B

    char* wsb = (char*)d_ws;
    __hip_bfloat16* h2 = (__hip_bfloat16*)wsb;              //  0 .. 16,000,000
    float* ai     = (float*)(wsb + 16000000);               // 1,000,000 B
    float* aj     = (float*)(wsb + 17000000);               // 1,000,000 B
    float* ssum   = (float*)(wsb + 18000000);               // 1,000,000 B
    unsigned* csrd = (unsigned*)(wsb + 19000000);           // 16,000,000 B (5 streams x 3.2MB)
    int* ghist    = (int*)(wsb + 35000000);                 // 306,544 B
    int* base2    = (int*)(wsb + 35310000);                 // 306,544 B
    int* btot     = (int*)(wsb + 35620000);                 // 1,564 B
    int* bbase    = (int*)(wsb + 35622000);                 // 1,564 B
    int* rowStart = (int*)(wsb + 35624000);                 // 200,004 B -> end ~35.83 MB

    const int B = 256;

    hist_kernel<<<K1_BLOCKS, 1024, 0, stream>>>(ei, fedge, ghist, lofs);
    hfused_kernel<<<(N_NODES / 2 * 8 + B - 1) / B, B, 0, stream>>>(x, W, att, h2, ai, aj);
    colsum_kernel<<<NBUCK, 256, 0, stream>>>(ghist, btot);
    bscan2_kernel<<<1, 512, 0, stream>>>(btot, bbase);
    colscan_kernel<<<NBUCK, 256, 0, stream>>>(ghist, bbase, base2);
    place_kernel<<<K1_BLOCKS, 1024, 0, stream>>>(ei, lofs, base2, edge_attr,
                                                 ai, aj, att, staged);
    build_kernel<<<NBUCK, 256, 0, stream>>>(staged, btot, bbase, csrd, rowStart);
    out_kernel<<<N_NODES / 8, 320, 0, stream>>>(h2, csrd, rowStart, out_buf, ssum);
    alpha_kernel<<<(N_EDGES * DIMS + B - 1) / B, B, 0, stream>>>(ei, edge_attr, ai, aj, att,
                                                                 ssum, alpha_buf);
}

// Round 20
// 149.495 us; speedup vs baseline: 1.1435x; 1.0172x over previous
//
#include <hip/hip_runtime.h>
#include <hip/hip_bf16.h>
#include <math.h>

#define N_NODES 50000
#define N_EDGES 800000
#define DIMS 5
#define IN_C 32
#define OUT_C 32
#define FEAT 160            // DIMS*OUT_C
#define ATT_LD 65           // 2*OUT_C+1
#define NEG_SLOPE 0.2f
#define BSHIFT 7
#define BROWS 128                                   // rows per bucket
#define NBUCK ((N_NODES + BROWS - 1) / BROWS)       // 391
#define CAP 2560                                    // max edges/bucket (mean 2048, +11 sigma)
#define K1_EPB 4096
#define K1_BLOCKS ((N_EDGES + K1_EPB - 1) / K1_EPB) // 196

// ---- K1: per-block LDS histogram + per-edge local rank; fedge conversion ----
__global__ __launch_bounds__(1024) void hist_kernel(
        const int* __restrict__ ei, float* __restrict__ fedge,
        int* __restrict__ ghist, unsigned short* __restrict__ lofs) {
    __shared__ int hist[NBUCK];
    int blk = blockIdx.x, t = threadIdx.x;
    if (t < NBUCK) hist[t] = 0;
    __syncthreads();
#pragma unroll
    for (int u = 0; u < 4; ++u) {
        int e = blk * K1_EPB + u * 1024 + t;
        if (e < N_EDGES) {
            int r = ei[e];
            int c = ei[N_EDGES + e];
            __builtin_nontemporal_store((float)r, &fedge[e]);
            __builtin_nontemporal_store((float)c, &fedge[N_EDGES + e]);
            int b = r >> BSHIFT;
            int lo = atomicAdd(&hist[b], 1);
            lofs[e] = (unsigned short)lo;
        }
    }
    __syncthreads();
    if (t < NBUCK) ghist[blk * NBUCK + t] = hist[t];
}

// ---- K2a: column sums -> btot[b] ----
__global__ void colsum_kernel(const int* __restrict__ ghist, int* __restrict__ btot) {
    __shared__ int red[256];
    int b = blockIdx.x, t = threadIdx.x;
    int s = 0;
    for (int blk = t; blk < K1_BLOCKS; blk += 256) s += ghist[blk * NBUCK + b];
    red[t] = s;
    __syncthreads();
    for (int off = 128; off > 0; off >>= 1) {
        if (t < off) red[t] += red[t + off];
        __syncthreads();
    }
    if (t == 0) btot[b] = red[0];
}

// ---- K2b: exclusive scan of btot -> bbase ----
__global__ void bscan2_kernel(const int* __restrict__ btot, int* __restrict__ bbase) {
    __shared__ int buf[512];
    int t = threadIdx.x;
    int v = (t < NBUCK) ? btot[t] : 0;
    buf[t] = v;
    __syncthreads();
    for (int off = 1; off < 512; off <<= 1) {
        int add = (t >= off) ? buf[t - off] : 0;
        __syncthreads();
        buf[t] += add;
        __syncthreads();
    }
    if (t < NBUCK) bbase[t] = buf[t] - v;
}

// ---- K2c: per-bucket exclusive scan over blocks -> base2[blk][b] ----
__global__ void colscan_kernel(const int* __restrict__ ghist, const int* __restrict__ bbase,
                               int* __restrict__ base2) {
    __shared__ int buf[256];
    int b = blockIdx.x, t = threadIdx.x;
    int v = (t < K1_BLOCKS) ? ghist[t * NBUCK + b] : 0;
    buf[t] = v;
    __syncthreads();
    for (int off = 1; off < 256; off <<= 1) {
        int add = (t >= off) ? buf[t - off] : 0;
        __syncthreads();
        buf[t] += add;
        __syncthreads();
    }
    if (t < K1_BLOCKS) base2[t * NBUCK + b] = bbase[b] + buf[t] - v;
}

// ---- K3: place edges into bucket-sorted staged[] with all 5 es embedded.
//      Flat geometry: 1 edge/thread, 3125 blocks -> full occupancy (TLP hides
//      the gather latency). base2 row is L1-resident; att loads are uniform. ----
__global__ __launch_bounds__(256) void place_kernel(
        const int* __restrict__ ei, const unsigned short* __restrict__ lofs,
        const int* __restrict__ base2,
        const float* __restrict__ edge_attr,
        const float* __restrict__ ai, const float* __restrict__ aj,
        const float* __restrict__ att,
        int4* __restrict__ staged) {
    int e = blockIdx.x * 256 + threadIdx.x;
    if (e >= N_EDGES) return;
    int r = ei[e];
    int c = ei[N_EDGES + e];
    int pos = base2[(e / K1_EPB) * NBUCK + (r >> BSHIFT)] + (int)lofs[e];
    const float* air = ai + r * DIMS;
    const float* ajr = aj + c * DIMS;
    const float* ea  = edge_attr + (size_t)e * DIMS;
    unsigned es[DIMS];
#pragma unroll
    for (int d = 0; d < DIMS; ++d) {
        float s = air[d] + ajr[d] + ea[d] * att[d * ATT_LD + 2 * OUT_C];
        s = (s > 0.f) ? s : NEG_SLOPE * s;
        __hip_bfloat16 h = __float2bfloat16(__expf(s));
        es[d] = (unsigned)*(unsigned short*)&h;
    }
    int4 st;
    st.x = c | ((r & (BROWS - 1)) << 16);
    st.y = (int)(es[0] | (es[1] << 16));
    st.z = (int)(es[2] | (es[3] << 16));
    st.w = (int)es[4];
    staged[pos] = st;
}

// ---- build: per-bucket CSR in LDS -> rowStart + 5-stream packed csrd ----
__global__ __launch_bounds__(256) void build_kernel(
        const int4* __restrict__ staged, const int* __restrict__ btot,
        const int* __restrict__ bbase,
        unsigned* __restrict__ csrd, int* __restrict__ rowStart) {
    __shared__ int4 sst[CAP];
    __shared__ int rcount[BROWS];
    __shared__ int rexcl[BROWS];
    __shared__ int sbuf[BROWS];
    int b = blockIdx.x;
    int t = threadIdx.x;
    int cnt  = btot[b];
    int base = bbase[b];
    const int4* sg = staged + base;
    for (int i = t; i < cnt; i += 256) sst[i] = sg[i];
    if (t < BROWS) rcount[t] = 0;
    __syncthreads();
    for (int i = t; i < cnt; i += 256)
        atomicAdd(&rcount[((unsigned)sst[i].x >> 16) & (BROWS - 1)], 1);
    __syncthreads();
    if (t < BROWS) sbuf[t] = rcount[t];
    __syncthreads();
    for (int off = 1; off < BROWS; off <<= 1) {
        int add = (t < BROWS && t >= off) ? sbuf[t - off] : 0;
        __syncthreads();
        if (t < BROWS) sbuf[t] += add;
        __syncthreads();
    }
    if (t < BROWS) {
        rexcl[t] = sbuf[t] - rcount[t];
        int idx = b * BROWS + t;
        if (idx <= N_NODES) rowStart[idx] = base + rexcl[t];
        rcount[t] = 0;                 // reuse as per-row cursor
    }
    __syncthreads();
    for (int i = t; i < cnt; i += 256) {
        int4 p = sst[i];
        int rl = ((unsigned)p.x >> 16) & (BROWS - 1);
        unsigned c = (unsigned)p.x & 0xffffu;
        int lp = atomicAdd(&rcount[rl], 1);
        int pos = base + rexcl[rl] + lp;
        unsigned es0 = (unsigned)p.y & 0xffffu;
        unsigned es1 = (unsigned)p.y >> 16;
        unsigned es2v = (unsigned)p.z & 0xffffu;
        unsigned es3 = (unsigned)p.z >> 16;
        unsigned es4 = (unsigned)p.w & 0xffffu;
        csrd[0 * N_EDGES + pos] = c | (es0 << 16);
        csrd[1 * N_EDGES + pos] = c | (es1 << 16);
        csrd[2 * N_EDGES + pos] = c | (es2v << 16);
        csrd[3 * N_EDGES + pos] = c | (es3 << 16);
        csrd[4 * N_EDGES + pos] = c | (es4 << 16);
    }
}

// ---- fused h (bf16) + ai/aj. thread = (node-pair, og); W staged in LDS (20 KB) ----
__global__ __launch_bounds__(256) void hfused_kernel(
        const float* __restrict__ x, const float* __restrict__ W,
        const float* __restrict__ att,
        __hip_bfloat16* __restrict__ h2,
        float* __restrict__ ai, float* __restrict__ aj) {
    __shared__ float sW[DIMS * IN_C * OUT_C];   // 5120 f32 = 20,480 B
    int tid = threadIdx.x;
    {
        const float4* Wg = (const float4*)W;
        float4* sW4 = (float4*)sW;
#pragma unroll
        for (int j = 0; j < 5; ++j)
            sW4[j * 256 + tid] = Wg[j * 256 + tid];
    }
    __syncthreads();

    int idx = blockIdx.x * 256 + tid;
    int pr = idx >> 3;                 // node pair
    int og = idx & 7;
    int n0 = pr * 2;
    if (n0 >= N_NODES) return;         // safe: after staging+barrier
    const float4* xr0 = (const float4*)(x + (size_t)n0 * FEAT);
    const float4* xr1 = xr0 + 40;

    float acc0[DIMS][4], acc1[DIMS][4];
#pragma unroll
    for (int d = 0; d < DIMS; ++d)
#pragma unroll
        for (int q = 0; q < 4; ++q) { acc0[d][q] = 0.f; acc1[d][q] = 0.f; }

#pragma unroll
    for (int ib = 0; ib < 8; ++ib) {
        float xs0[20], xs1[20];
#pragma unroll
        for (int q = 0; q < 5; ++q) {
            float4 v0 = xr0[ib * 5 + q];
            float4 v1 = xr1[ib * 5 + q];
            xs0[q * 4 + 0] = v0.x; xs0[q * 4 + 1] = v0.y;
            xs0[q * 4 + 2] = v0.z; xs0[q * 4 + 3] = v0.w;
            xs1[q * 4 + 0] = v1.x; xs1[q * 4 + 1] = v1.y;
            xs1[q * 4 + 2] = v1.z; xs1[q * 4 + 3] = v1.w;
        }
#pragma unroll
        for (int ii = 0; ii < 4; ++ii) {
            int i = ib * 4 + ii;
#pragma unroll
            for (int d = 0; d < DIMS; ++d) {
                float4 wv = *(const float4*)(sW + ((d * IN_C + i) * OUT_C) + og * 4);
                float xv0 = xs0[ii * 5 + d];
                float xv1 = xs1[ii * 5 + d];
                acc0[d][0] += xv0 * wv.x; acc0[d][1] += xv0 * wv.y;
                acc0[d][2] += xv0 * wv.z; acc0[d][3] += xv0 * wv.w;
                acc1[d][0] += xv1 * wv.x; acc1[d][1] += xv1 * wv.y;
                acc1[d][2] += xv1 * wv.z; acc1[d][3] += xv1 * wv.w;
            }
        }
    }

    __hip_bfloat16* hp0 = h2 + (size_t)n0 * FEAT + og * 4;
#pragma unroll
    for (int d = 0; d < DIMS; ++d) {
        union { __hip_bfloat16 h[4]; uint2 u; } pk;
        pk.h[0] = __float2bfloat16(acc0[d][0]);
        pk.h[1] = __float2bfloat16(acc0[d][1]);
        pk.h[2] = __float2bfloat16(acc0[d][2]);
        pk.h[3] = __float2bfloat16(acc0[d][3]);
        *(uint2*)(hp0 + d * OUT_C) = pk.u;
    }
    __hip_bfloat16* hp1 = hp0 + FEAT;
#pragma unroll
    for (int d = 0; d < DIMS; ++d) {
        union { __hip_bfloat16 h[4]; uint2 u; } pk;
        pk.h[0] = __float2bfloat16(acc1[d][0]);
        pk.h[1] = __float2bfloat16(acc1[d][1]);
        pk.h[2] = __float2bfloat16(acc1[d][2]);
        pk.h[3] = __float2bfloat16(acc1[d][3]);
        *(uint2*)(hp1 + d * OUT_C) = pk.u;
    }

    float pa0[DIMS], pb0[DIMS], pa1[DIMS], pb1[DIMS];
#pragma unroll
    for (int d = 0; d < DIMS; ++d) {
        const float* at = att + d * ATT_LD + og * 4;
        const float* bt = at + OUT_C;
        pa0[d] = acc0[d][0] * at[0] + acc0[d][1] * at[1] + acc0[d][2] * at[2] + acc0[d][3] * at[3];
        pb0[d] = acc0[d][0] * bt[0] + acc0[d][1] * bt[1] + acc0[d][2] * bt[2] + acc0[d][3] * bt[3];
        pa1[d] = acc1[d][0] * at[0] + acc1[d][1] * at[1] + acc1[d][2] * at[2] + acc1[d][3] * at[3];
        pb1[d] = acc1[d][0] * bt[0] + acc1[d][1] * bt[1] + acc1[d][2] * bt[2] + acc1[d][3] * bt[3];
    }
#pragma unroll
    for (int m = 1; m < 8; m <<= 1) {
#pragma unroll
        for (int d = 0; d < DIMS; ++d) {
            pa0[d] += __shfl_xor(pa0[d], m, 8);
            pb0[d] += __shfl_xor(pb0[d], m, 8);
            pa1[d] += __shfl_xor(pa1[d], m, 8);
            pb1[d] += __shfl_xor(pb1[d], m, 8);
        }
    }
    if (og == 0) {
#pragma unroll
        for (int d = 0; d < DIMS; ++d) {
            ai[n0 * DIMS + d] = pa0[d];
            aj[n0 * DIMS + d] = pb0[d];
            ai[(n0 + 1) * DIMS + d] = pa1[d];
            aj[(n0 + 1) * DIMS + d] = pb1[d];
        }
    }
}

__device__ inline float bf2f(unsigned short u) {
    return __uint_as_float(((unsigned)u) << 16);
}

// ---- out: 320-thr blocks, 8 nodes/block, 40 lanes/node; packed per-d csr stream,
//      masked final batch + prefetch ----
__global__ __launch_bounds__(320) void out_kernel(
        const __hip_bfloat16* __restrict__ h2,
        const unsigned* __restrict__ csrd,
        const int* __restrict__ rowStart,
        float* __restrict__ out, float* __restrict__ ssum) {
    int g = threadIdx.x / 40;          // node group 0..7
    int l = threadIdx.x - g * 40;      // 0..39
    int node = blockIdx.x * 8 + g;
    int d = l >> 3;                    // 8 lanes per d
    const unsigned* cs = csrd + (size_t)d * N_EDGES;
    int start = rowStart[node];
    int end   = rowStart[node + 1];
    float a0 = 0.f, a1 = 0.f, a2 = 0.f, a3 = 0.f, ss = 0.f;
    if (end > start) {
        int last = end - 1;
        int k = start;
        unsigned ceA[8];
#pragma unroll
        for (int u = 0; u < 8; ++u) {
            int kk = k + u;
            ceA[u] = cs[kk <= last ? kk : last];
        }
        while (true) {
            int kn = k + 8;
            bool more = (kn < end);
            float av[8]; uint2 hv[8]; unsigned ceB[8];
#pragma unroll
            for (int u = 0; u < 8; ++u) {
                float a = bf2f((unsigned short)(ceA[u] >> 16));
                av[u] = (k + u < end) ? a : 0.f;
            }
#pragma unroll
            for (int u = 0; u < 8; ++u)
                hv[u] = *(const uint2*)(h2 + (size_t)(ceA[u] & 0xffffu) * FEAT + l * 4);
            if (more) {
#pragma unroll
                for (int u = 0; u < 8; ++u) {
                    int kk = kn + u;
                    ceB[u] = cs[kk <= last ? kk : last];
                }
            }
#pragma unroll
            for (int u = 0; u < 8; ++u) {
                float a = av[u];
                ss += a;
                a0 += a * __uint_as_float(hv[u].x << 16);
                a1 += a * __uint_as_float(hv[u].x & 0xffff0000u);
                a2 += a * __uint_as_float(hv[u].y << 16);
                a3 += a * __uint_as_float(hv[u].y & 0xffff0000u);
            }
            if (!more) break;
            k = kn;
#pragma unroll
            for (int u = 0; u < 8; ++u) ceA[u] = ceB[u];
        }
    }
    float inv = 1.f / (ss + 1e-16f);
    union { float f[4]; unsigned long long u[2]; } o;
    o.f[0] = a0 * inv; o.f[1] = a1 * inv; o.f[2] = a2 * inv; o.f[3] = a3 * inv;
    unsigned long long* op = (unsigned long long*)(out + (size_t)node * FEAT + l * 4);
    __builtin_nontemporal_store(o.u[0], op);
    __builtin_nontemporal_store(o.u[1], op + 1);
    if ((l & 7) == 0) ssum[node * DIMS + d] = ss;
}

// ---- alpha: recompute es coalesced (edge order), divide by ssum[row] ----
__global__ void alpha_kernel(const int* __restrict__ ei,
                             const float* __restrict__ edge_attr,
                             const float* __restrict__ ai, const float* __restrict__ aj,
                             const float* __restrict__ att,
                             const float* __restrict__ ssum,
                             float* __restrict__ alpha_buf) {
    int idx = blockIdx.x * blockDim.x + threadIdx.x;
    if (idx >= N_EDGES * DIMS) return;
    int e = idx / DIMS;
    int d = idx - e * DIMS;
    int r = ei[e];
    int c = ei[N_EDGES + e];
    float s = ai[r * DIMS + d] + aj[c * DIMS + d]
            + edge_attr[idx] * att[d * ATT_LD + 2 * OUT_C];
    s = (s > 0.f) ? s : NEG_SLOPE * s;
    __hip_bfloat16 h = __float2bfloat16(__expf(s));
    float a = bf2f(*(unsigned short*)&h) / (ssum[r * DIMS + d] + 1e-16f);
    __builtin_nontemporal_store(a, &alpha_buf[idx]);
}

extern "C" void kernel_launch(void* const* d_in, const int* in_sizes, int n_in,
                              void* d_out, int out_size, void* d_ws, size_t ws_size,
                              hipStream_t stream) {
    const float* x         = (const float*)d_in[0];
    const int*   ei        = (const int*)d_in[1];
    const float* edge_attr = (const float*)d_in[2];
    const float* W         = (const float*)d_in[3];
    const float* att       = (const float*)d_in[4];

    float* out_buf   = (float*)d_out;                       // 8,000,000 f32
    float* alpha_buf = out_buf + (size_t)N_NODES * FEAT;    // 4,000,000 f32 (scratch until alpha)
    float* fedge     = alpha_buf + (size_t)N_EDGES * DIMS;  // 1,600,000 f32

    // scratch inside the alpha output region (dead until alpha_kernel runs last):
    int4* staged = (int4*)alpha_buf;                        // 12,800,000 B
    unsigned short* lofs = (unsigned short*)((char*)alpha_buf + 12800000); // 1,600,000 B

    char* wsb = (char*)d_ws;
    __hip_bfloat16* h2 = (__hip_bfloat16*)wsb;              //  0 .. 16,000,000
    float* ai     = (float*)(wsb + 16000000);               // 1,000,000 B
    float* aj     = (float*)(wsb + 17000000);               // 1,000,000 B
    float* ssum   = (float*)(wsb + 18000000);               // 1,000,000 B
    unsigned* csrd = (unsigned*)(wsb + 19000000);           // 16,000,000 B (5 streams x 3.2MB)
    int* ghist    = (int*)(wsb + 35000000);                 // 306,544 B
    int* base2    = (int*)(wsb + 35310000);                 // 306,544 B
    int* btot     = (int*)(wsb + 35620000);                 // 1,564 B
    int* bbase    = (int*)(wsb + 35622000);                 // 1,564 B
    int* rowStart = (int*)(wsb + 35624000);                 // 200,004 B -> end ~35.83 MB

    const int B = 256;

    hist_kernel<<<K1_BLOCKS, 1024, 0, stream>>>(ei, fedge, ghist, lofs);
    hfused_kernel<<<(N_NODES / 2 * 8 + B - 1) / B, B, 0, stream>>>(x, W, att, h2, ai, aj);
    colsum_kernel<<<NBUCK, 256, 0, stream>>>(ghist, btot);
    bscan2_kernel<<<1, 512, 0, stream>>>(btot, bbase);
    colscan_kernel<<<NBUCK, 256, 0, stream>>>(ghist, bbase, base2);
    place_kernel<<<(N_EDGES + B - 1) / B, B, 0, stream>>>(ei, lofs, base2, edge_attr,
                                                          ai, aj, att, staged);
    build_kernel<<<NBUCK, 256, 0, stream>>>(staged, btot, bbase, csrd, rowStart);
    out_kernel<<<N_NODES / 8, 320, 0, stream>>>(h2, csrd, rowStart, out_buf, ssum);
    alpha_kernel<<<(N_EDGES * DIMS + B - 1) / B, B, 0, stream>>>(ei, edge_attr, ai, aj, att,
                                                                 ssum, alpha_buf);
}

// Round 21
// 146.679 us; speedup vs baseline: 1.1655x; 1.0192x over previous
//
#include <hip/hip_runtime.h>
#include <hip/hip_bf16.h>
#include <math.h>

#define N_NODES 50000
#define N_EDGES 800000
#define DIMS 5
#define IN_C 32
#define OUT_C 32
#define FEAT 160            // DIMS*OUT_C
#define ATT_LD 65           // 2*OUT_C+1
#define NEG_SLOPE 0.2f
#define BSHIFT 7
#define BROWS 128                                   // rows per bucket
#define NBUCK ((N_NODES + BROWS - 1) / BROWS)       // 391
#define CAP 2560                                    // max edges/bucket (mean 2048, +11 sigma)
#define K1_EPB 4096
#define K1_BLOCKS ((N_EDGES + K1_EPB - 1) / K1_EPB) // 196

// ---- K1: per-block LDS histogram + per-edge local rank; fedge conversion ----
__global__ __launch_bounds__(1024) void hist_kernel(
        const int* __restrict__ ei, float* __restrict__ fedge,
        int* __restrict__ ghist, unsigned short* __restrict__ lofs) {
    __shared__ int hist[NBUCK];
    int blk = blockIdx.x, t = threadIdx.x;
    if (t < NBUCK) hist[t] = 0;
    __syncthreads();
#pragma unroll
    for (int u = 0; u < 4; ++u) {
        int e = blk * K1_EPB + u * 1024 + t;
        if (e < N_EDGES) {
            int r = ei[e];
            int c = ei[N_EDGES + e];
            __builtin_nontemporal_store((float)r, &fedge[e]);
            __builtin_nontemporal_store((float)c, &fedge[N_EDGES + e]);
            int b = r >> BSHIFT;
            int lo = atomicAdd(&hist[b], 1);
            lofs[e] = (unsigned short)lo;
        }
    }
    __syncthreads();
    if (t < NBUCK) ghist[blk * NBUCK + t] = hist[t];
}

// ---- K2a: column sums -> btot[b] ----
__global__ void colsum_kernel(const int* __restrict__ ghist, int* __restrict__ btot) {
    __shared__ int red[256];
    int b = blockIdx.x, t = threadIdx.x;
    int s = 0;
    for (int blk = t; blk < K1_BLOCKS; blk += 256) s += ghist[blk * NBUCK + b];
    red[t] = s;
    __syncthreads();
    for (int off = 128; off > 0; off >>= 1) {
        if (t < off) red[t] += red[t + off];
        __syncthreads();
    }
    if (t == 0) btot[b] = red[0];
}

// ---- K2b: exclusive scan of btot -> bbase ----
__global__ void bscan2_kernel(const int* __restrict__ btot, int* __restrict__ bbase) {
    __shared__ int buf[512];
    int t = threadIdx.x;
    int v = (t < NBUCK) ? btot[t] : 0;
    buf[t] = v;
    __syncthreads();
    for (int off = 1; off < 512; off <<= 1) {
        int add = (t >= off) ? buf[t - off] : 0;
        __syncthreads();
        buf[t] += add;
        __syncthreads();
    }
    if (t < NBUCK) bbase[t] = buf[t] - v;
}

// ---- K2c: per-bucket exclusive scan over blocks -> base2[blk][b] ----
__global__ void colscan_kernel(const int* __restrict__ ghist, const int* __restrict__ bbase,
                               int* __restrict__ base2) {
    __shared__ int buf[256];
    int b = blockIdx.x, t = threadIdx.x;
    int v = (t < K1_BLOCKS) ? ghist[t * NBUCK + b] : 0;
    buf[t] = v;
    __syncthreads();
    for (int off = 1; off < 256; off <<= 1) {
        int add = (t >= off) ? buf[t - off] : 0;
        __syncthreads();
        buf[t] += add;
        __syncthreads();
    }
    if (t < K1_BLOCKS) base2[t * NBUCK + b] = bbase[b] + buf[t] - v;
}

// ---- K3: place. Chunk's entries bucket-sorted in LDS, then written out as
//      CONTIGUOUS runs (full-line stores, single-block ownership -> L2 merge).
//      st.x layout: c(16) | rl(7)<<16 | b(9)<<23 ----
__global__ __launch_bounds__(1024) void place_kernel(
        const int* __restrict__ ei, const unsigned short* __restrict__ lofs,
        const int* __restrict__ base2, const int* __restrict__ ghist,
        const float* __restrict__ edge_attr,
        const float* __restrict__ ai, const float* __restrict__ aj,
        const float* __restrict__ att,
        int4* __restrict__ staged) {
    __shared__ int4 sstg[K1_EPB];          // 64 KB
    __shared__ int lbase[NBUCK];
    __shared__ int lexcl[NBUCK];
    __shared__ int sbuf[512];
    __shared__ float satte[DIMS];
    int blk = blockIdx.x, t = threadIdx.x;
    if (t < NBUCK) lbase[t] = base2[blk * NBUCK + t];
    if (t < DIMS) satte[t] = att[t * ATT_LD + 2 * OUT_C];
    if (t < 512) sbuf[t] = (t < NBUCK) ? ghist[blk * NBUCK + t] : 0;
    __syncthreads();
    int v = (t < 512) ? sbuf[t] : 0;
    for (int off = 1; off < 512; off <<= 1) {
        int add = (t < 512 && t >= off) ? sbuf[t - off] : 0;
        __syncthreads();
        if (t < 512) sbuf[t] += add;
        __syncthreads();
    }
    if (t < NBUCK) lexcl[t] = sbuf[t] - v;
    __syncthreads();

    int ebase = blk * K1_EPB;
    int cnt2 = N_EDGES - ebase; if (cnt2 > K1_EPB) cnt2 = K1_EPB;

#pragma unroll
    for (int u = 0; u < 4; ++u) {
        int i = u * 1024 + t;
        if (i < cnt2) {
            int e = ebase + i;
            int r = ei[e];
            int c = ei[N_EDGES + e];
            int b = r >> BSHIFT;
            const float* air = ai + r * DIMS;
            const float* ajr = aj + c * DIMS;
            const float* ea  = edge_attr + (size_t)e * DIMS;
            unsigned es[DIMS];
#pragma unroll
            for (int d = 0; d < DIMS; ++d) {
                float s = air[d] + ajr[d] + ea[d] * satte[d];
                s = (s > 0.f) ? s : NEG_SLOPE * s;
                __hip_bfloat16 h = __float2bfloat16(__expf(s));
                es[d] = (unsigned)*(unsigned short*)&h;
            }
            int4 st;
            st.x = c | ((r & (BROWS - 1)) << 16) | (b << 23);
            st.y = (int)(es[0] | (es[1] << 16));
            st.z = (int)(es[2] | (es[3] << 16));
            st.w = (int)es[4];
            sstg[lexcl[b] + (int)lofs[e]] = st;
        }
    }
    __syncthreads();
    // linear write-out: consecutive i -> consecutive dest within each bucket run
#pragma unroll
    for (int u = 0; u < 4; ++u) {
        int i = u * 1024 + t;
        if (i < cnt2) {
            int4 p = sstg[i];
            int b = (unsigned)p.x >> 23;
            staged[lbase[b] + (i - lexcl[b])] = p;
        }
    }
}

// ---- build: per-bucket CSR in LDS -> rowStart + 5-stream packed csrd ----
__global__ __launch_bounds__(256) void build_kernel(
        const int4* __restrict__ staged, const int* __restrict__ btot,
        const int* __restrict__ bbase,
        unsigned* __restrict__ csrd, int* __restrict__ rowStart) {
    __shared__ int4 sst[CAP];
    __shared__ int rcount[BROWS];
    __shared__ int rexcl[BROWS];
    __shared__ int sbuf[BROWS];
    int b = blockIdx.x;
    int t = threadIdx.x;
    int cnt  = btot[b];
    int base = bbase[b];
    const int4* sg = staged + base;
    for (int i = t; i < cnt; i += 256) sst[i] = sg[i];
    if (t < BROWS) rcount[t] = 0;
    __syncthreads();
    for (int i = t; i < cnt; i += 256)
        atomicAdd(&rcount[((unsigned)sst[i].x >> 16) & (BROWS - 1)], 1);
    __syncthreads();
    if (t < BROWS) sbuf[t] = rcount[t];
    __syncthreads();
    for (int off = 1; off < BROWS; off <<= 1) {
        int add = (t < BROWS && t >= off) ? sbuf[t - off] : 0;
        __syncthreads();
        if (t < BROWS) sbuf[t] += add;
        __syncthreads();
    }
    if (t < BROWS) {
        rexcl[t] = sbuf[t] - rcount[t];
        int idx = b * BROWS + t;
        if (idx <= N_NODES) rowStart[idx] = base + rexcl[t];
        rcount[t] = 0;                 // reuse as per-row cursor
    }
    __syncthreads();
    for (int i = t; i < cnt; i += 256) {
        int4 p = sst[i];
        int rl = ((unsigned)p.x >> 16) & (BROWS - 1);
        unsigned c = (unsigned)p.x & 0xffffu;
        int lp = atomicAdd(&rcount[rl], 1);
        int pos = base + rexcl[rl] + lp;
        unsigned es0 = (unsigned)p.y & 0xffffu;
        unsigned es1 = (unsigned)p.y >> 16;
        unsigned es2v = (unsigned)p.z & 0xffffu;
        unsigned es3 = (unsigned)p.z >> 16;
        unsigned es4 = (unsigned)p.w & 0xffffu;
        csrd[0 * N_EDGES + pos] = c | (es0 << 16);
        csrd[1 * N_EDGES + pos] = c | (es1 << 16);
        csrd[2 * N_EDGES + pos] = c | (es2v << 16);
        csrd[3 * N_EDGES + pos] = c | (es3 << 16);
        csrd[4 * N_EDGES + pos] = c | (es4 << 16);
    }
}

// ---- fused h (bf16) + ai/aj. thread = (node-pair, og); W staged in LDS (20 KB) ----
__global__ __launch_bounds__(256) void hfused_kernel(
        const float* __restrict__ x, const float* __restrict__ W,
        const float* __restrict__ att,
        __hip_bfloat16* __restrict__ h2,
        float* __restrict__ ai, float* __restrict__ aj) {
    __shared__ float sW[DIMS * IN_C * OUT_C];   // 5120 f32 = 20,480 B
    int tid = threadIdx.x;
    {
        const float4* Wg = (const float4*)W;
        float4* sW4 = (float4*)sW;
#pragma unroll
        for (int j = 0; j < 5; ++j)
            sW4[j * 256 + tid] = Wg[j * 256 + tid];
    }
    __syncthreads();

    int idx = blockIdx.x * 256 + tid;
    int pr = idx >> 3;                 // node pair
    int og = idx & 7;
    int n0 = pr * 2;
    if (n0 >= N_NODES) return;         // safe: after staging+barrier
    const float4* xr0 = (const float4*)(x + (size_t)n0 * FEAT);
    const float4* xr1 = xr0 + 40;

    float acc0[DIMS][4], acc1[DIMS][4];
#pragma unroll
    for (int d = 0; d < DIMS; ++d)
#pragma unroll
        for (int q = 0; q < 4; ++q) { acc0[d][q] = 0.f; acc1[d][q] = 0.f; }

#pragma unroll
    for (int ib = 0; ib < 8; ++ib) {
        float xs0[20], xs1[20];
#pragma unroll
        for (int q = 0; q < 5; ++q) {
            float4 v0 = xr0[ib * 5 + q];
            float4 v1 = xr1[ib * 5 + q];
            xs0[q * 4 + 0] = v0.x; xs0[q * 4 + 1] = v0.y;
            xs0[q * 4 + 2] = v0.z; xs0[q * 4 + 3] = v0.w;
            xs1[q * 4 + 0] = v1.x; xs1[q * 4 + 1] = v1.y;
            xs1[q * 4 + 2] = v1.z; xs1[q * 4 + 3] = v1.w;
        }
#pragma unroll
        for (int ii = 0; ii < 4; ++ii) {
            int i = ib * 4 + ii;
#pragma unroll
            for (int d = 0; d < DIMS; ++d) {
                float4 wv = *(const float4*)(sW + ((d * IN_C + i) * OUT_C) + og * 4);
                float xv0 = xs0[ii * 5 + d];
                float xv1 = xs1[ii * 5 + d];
                acc0[d][0] += xv0 * wv.x; acc0[d][1] += xv0 * wv.y;
                acc0[d][2] += xv0 * wv.z; acc0[d][3] += xv0 * wv.w;
                acc1[d][0] += xv1 * wv.x; acc1[d][1] += xv1 * wv.y;
                acc1[d][2] += xv1 * wv.z; acc1[d][3] += xv1 * wv.w;
            }
        }
    }

    __hip_bfloat16* hp0 = h2 + (size_t)n0 * FEAT + og * 4;
#pragma unroll
    for (int d = 0; d < DIMS; ++d) {
        union { __hip_bfloat16 h[4]; uint2 u; } pk;
        pk.h[0] = __float2bfloat16(acc0[d][0]);
        pk.h[1] = __float2bfloat16(acc0[d][1]);
        pk.h[2] = __float2bfloat16(acc0[d][2]);
        pk.h[3] = __float2bfloat16(acc0[d][3]);
        *(uint2*)(hp0 + d * OUT_C) = pk.u;
    }
    __hip_bfloat16* hp1 = hp0 + FEAT;
#pragma unroll
    for (int d = 0; d < DIMS; ++d) {
        union { __hip_bfloat16 h[4]; uint2 u; } pk;
        pk.h[0] = __float2bfloat16(acc1[d][0]);
        pk.h[1] = __float2bfloat16(acc1[d][1]);
        pk.h[2] = __float2bfloat16(acc1[d][2]);
        pk.h[3] = __float2bfloat16(acc1[d][3]);
        *(uint2*)(hp1 + d * OUT_C) = pk.u;
    }

    float pa0[DIMS], pb0[DIMS], pa1[DIMS], pb1[DIMS];
#pragma unroll
    for (int d = 0; d < DIMS; ++d) {
        const float* at = att + d * ATT_LD + og * 4;
        const float* bt = at + OUT_C;
        pa0[d] = acc0[d][0] * at[0] + acc0[d][1] * at[1] + acc0[d][2] * at[2] + acc0[d][3] * at[3];
        pb0[d] = acc0[d][0] * bt[0] + acc0[d][1] * bt[1] + acc0[d][2] * bt[2] + acc0[d][3] * bt[3];
        pa1[d] = acc1[d][0] * at[0] + acc1[d][1] * at[1] + acc1[d][2] * at[2] + acc1[d][3] * at[3];
        pb1[d] = acc1[d][0] * bt[0] + acc1[d][1] * bt[1] + acc1[d][2] * bt[2] + acc1[d][3] * bt[3];
    }
#pragma unroll
    for (int m = 1; m < 8; m <<= 1) {
#pragma unroll
        for (int d = 0; d < DIMS; ++d) {
            pa0[d] += __shfl_xor(pa0[d], m, 8);
            pb0[d] += __shfl_xor(pb0[d], m, 8);
            pa1[d] += __shfl_xor(pa1[d], m, 8);
            pb1[d] += __shfl_xor(pb1[d], m, 8);
        }
    }
    if (og == 0) {
#pragma unroll
        for (int d = 0; d < DIMS; ++d) {
            ai[n0 * DIMS + d] = pa0[d];
            aj[n0 * DIMS + d] = pb0[d];
            ai[(n0 + 1) * DIMS + d] = pa1[d];
            aj[(n0 + 1) * DIMS + d] = pb1[d];
        }
    }
}

__device__ inline float bf2f(unsigned short u) {
    return __uint_as_float(((unsigned)u) << 16);
}

// ---- out: 320-thr blocks, 8 nodes/block, 40 lanes/node; packed per-d csr stream,
//      masked final batch + prefetch ----
__global__ __launch_bounds__(320) void out_kernel(
        const __hip_bfloat16* __restrict__ h2,
        const unsigned* __restrict__ csrd,
        const int* __restrict__ rowStart,
        float* __restrict__ out, float* __restrict__ ssum) {
    int g = threadIdx.x / 40;          // node group 0..7
    int l = threadIdx.x - g * 40;      // 0..39
    int node = blockIdx.x * 8 + g;
    int d = l >> 3;                    // 8 lanes per d
    const unsigned* cs = csrd + (size_t)d * N_EDGES;
    int start = rowStart[node];
    int end   = rowStart[node + 1];
    float a0 = 0.f, a1 = 0.f, a2 = 0.f, a3 = 0.f, ss = 0.f;
    if (end > start) {
        int last = end - 1;
        int k = start;
        unsigned ceA[8];
#pragma unroll
        for (int u = 0; u < 8; ++u) {
            int kk = k + u;
            ceA[u] = cs[kk <= last ? kk : last];
        }
        while (true) {
            int kn = k + 8;
            bool more = (kn < end);
            float av[8]; uint2 hv[8]; unsigned ceB[8];
#pragma unroll
            for (int u = 0; u < 8; ++u) {
                float a = bf2f((unsigned short)(ceA[u] >> 16));
                av[u] = (k + u < end) ? a : 0.f;
            }
#pragma unroll
            for (int u = 0; u < 8; ++u)
                hv[u] = *(const uint2*)(h2 + (size_t)(ceA[u] & 0xffffu) * FEAT + l * 4);
            if (more) {
#pragma unroll
                for (int u = 0; u < 8; ++u) {
                    int kk = kn + u;
                    ceB[u] = cs[kk <= last ? kk : last];
                }
            }
#pragma unroll
            for (int u = 0; u < 8; ++u) {
                float a = av[u];
                ss += a;
                a0 += a * __uint_as_float(hv[u].x << 16);
                a1 += a * __uint_as_float(hv[u].x & 0xffff0000u);
                a2 += a * __uint_as_float(hv[u].y << 16);
                a3 += a * __uint_as_float(hv[u].y & 0xffff0000u);
            }
            if (!more) break;
            k = kn;
#pragma unroll
            for (int u = 0; u < 8; ++u) ceA[u] = ceB[u];
        }
    }
    float inv = 1.f / (ss + 1e-16f);
    union { float f[4]; unsigned long long u[2]; } o;
    o.f[0] = a0 * inv; o.f[1] = a1 * inv; o.f[2] = a2 * inv; o.f[3] = a3 * inv;
    unsigned long long* op = (unsigned long long*)(out + (size_t)node * FEAT + l * 4);
    __builtin_nontemporal_store(o.u[0], op);
    __builtin_nontemporal_store(o.u[1], op + 1);
    if ((l & 7) == 0) ssum[node * DIMS + d] = ss;
}

// ---- alpha: recompute es coalesced (edge order), divide by ssum[row] ----
__global__ void alpha_kernel(const int* __restrict__ ei,
                             const float* __restrict__ edge_attr,
                             const float* __restrict__ ai, const float* __restrict__ aj,
                             const float* __restrict__ att,
                             const float* __restrict__ ssum,
                             float* __restrict__ alpha_buf) {
    int idx = blockIdx.x * blockDim.x + threadIdx.x;
    if (idx >= N_EDGES * DIMS) return;
    int e = idx / DIMS;
    int d = idx - e * DIMS;
    int r = ei[e];
    int c = ei[N_EDGES + e];
    float s = ai[r * DIMS + d] + aj[c * DIMS + d]
            + edge_attr[idx] * att[d * ATT_LD + 2 * OUT_C];
    s = (s > 0.f) ? s : NEG_SLOPE * s;
    __hip_bfloat16 h = __float2bfloat16(__expf(s));
    float a = bf2f(*(unsigned short*)&h) / (ssum[r * DIMS + d] + 1e-16f);
    __builtin_nontemporal_store(a, &alpha_buf[idx]);
}

extern "C" void kernel_launch(void* const* d_in, const int* in_sizes, int n_in,
                              void* d_out, int out_size, void* d_ws, size_t ws_size,
                              hipStream_t stream) {
    const float* x         = (const float*)d_in[0];
    const int*   ei        = (const int*)d_in[1];
    const float* edge_attr = (const float*)d_in[2];
    const float* W         = (const float*)d_in[3];
    const float* att       = (const float*)d_in[4];

    float* out_buf   = (float*)d_out;                       // 8,000,000 f32
    float* alpha_buf = out_buf + (size_t)N_NODES * FEAT;    // 4,000,000 f32 (scratch until alpha)
    float* fedge     = alpha_buf + (size_t)N_EDGES * DIMS;  // 1,600,000 f32

    // scratch inside the alpha output region (dead until alpha_kernel runs last):
    int4* staged = (int4*)alpha_buf;                        // 12,800,000 B
    unsigned short* lofs = (unsigned short*)((char*)alpha_buf + 12800000); // 1,600,000 B

    char* wsb = (char*)d_ws;
    __hip_bfloat16* h2 = (__hip_bfloat16*)wsb;              //  0 .. 16,000,000
    float* ai     = (float*)(wsb + 16000000);               // 1,000,000 B
    float* aj     = (float*)(wsb + 17000000);               // 1,000,000 B
    float* ssum   = (float*)(wsb + 18000000);               // 1,000,000 B
    unsigned* csrd = (unsigned*)(wsb + 19000000);           // 16,000,000 B (5 streams x 3.2MB)
    int* ghist    = (int*)(wsb + 35000000);                 // 306,544 B
    int* base2    = (int*)(wsb + 35310000);                 // 306,544 B
    int* btot     = (int*)(wsb + 35620000);                 // 1,564 B
    int* bbase    = (int*)(wsb + 35622000);                 // 1,564 B
    int* rowStart = (int*)(wsb + 35624000);                 // 200,004 B -> end ~35.83 MB

    const int B = 256;

    hist_kernel<<<K1_BLOCKS, 1024, 0, stream>>>(ei, fedge, ghist, lofs);
    hfused_kernel<<<(N_NODES / 2 * 8 + B - 1) / B, B, 0, stream>>>(x, W, att, h2, ai, aj);
    colsum_kernel<<<NBUCK, 256, 0, stream>>>(ghist, btot);
    bscan2_kernel<<<1, 512, 0, stream>>>(btot, bbase);
    colscan_kernel<<<NBUCK, 256, 0, stream>>>(ghist, bbase, base2);
    place_kernel<<<K1_BLOCKS, 1024, 0, stream>>>(ei, lofs, base2, ghist, edge_attr,
                                                 ai, aj, att, staged);
    build_kernel<<<NBUCK, 256, 0, stream>>>(staged, btot, bbase, csrd, rowStart);
    out_kernel<<<N_NODES / 8, 320, 0, stream>>>(h2, csrd, rowStart, out_buf, ssum);
    alpha_kernel<<<(N_EDGES * DIMS + B - 1) / B, B, 0, stream>>>(ei, edge_attr, ai, aj, att,
                                                                 ssum, alpha_buf);
}